// Round 1
// baseline (326.426 us; speedup 1.0000x reference)
//
#include <hip/hip_runtime.h>
#include <math.h>

#define NN 4096
#define CC 256
#define HH 8
#define DHD 32
#define EE 32768
#define FW 128   // bitset words per row (4096/32)

__device__ __forceinline__ int bucketf(int d){
  float l = log2f((float)d + 1.0f);
  int b = (int)floorf(l);
  return b < 0 ? 0 : (b > 8 ? 8 : b);
}

__global__ void k_deg(const int* __restrict__ src, const int* __restrict__ dst,
                      int* __restrict__ indeg, int* __restrict__ outdeg){
  int e = blockIdx.x*256 + threadIdx.x;
  if(e < EE){
    atomicAdd(&indeg[dst[e]], 1);
    atomicAdd(&outdeg[src[e]], 1);
  }
}

__global__ void k_xin(const float* __restrict__ x, const int* __restrict__ indeg,
                      const int* __restrict__ outdeg, const float* __restrict__ iemb,
                      const float* __restrict__ oemb, float* __restrict__ x_in){
  int n = blockIdx.x; int c = threadIdx.x;
  int bi = bucketf(indeg[n]);
  int bo = bucketf(outdeg[n]);
  x_in[n*CC+c] = x[n*CC+c] + iemb[bi*CC+c] + oemb[bo*CC+c];
}

__global__ void k_f1(const int* __restrict__ src, const int* __restrict__ dst,
                     unsigned* __restrict__ F1){
  int e = blockIdx.x*256 + threadIdx.x;
  if(e < EE){
    int s = src[e], d = dst[e];
    atomicOr(&F1[d*FW + (s>>5)], 1u << (s&31));
  }
}

__global__ void k_prop(const int* __restrict__ src, const int* __restrict__ dst,
                       const unsigned* __restrict__ Fin, unsigned* __restrict__ Fout){
  int id = blockIdx.x*256 + threadIdx.x;  // EE*FW threads
  int e = id >> 7, w = id & (FW-1);
  int s = src[e], d = dst[e];
  unsigned v = Fin[s*FW + w];
  if(v) atomicOr(&Fout[d*FW + w], v);
}

__global__ void k_spd(const int* __restrict__ src, const int* __restrict__ dst,
                      const unsigned* __restrict__ F1, const unsigned* __restrict__ F2,
                      const unsigned* __restrict__ F3, int* __restrict__ spd){
  int e = blockIdx.x*256 + threadIdx.x;
  if(e < EE){
    int s = src[e], d = dst[e];
    int wi = s*FW + (d>>5); unsigned b = 1u << (d&31);
    int v = 4;
    if (F3[wi] & b) v = 3;
    if (F2[wi] & b) v = 2;
    if (F1[wi] & b) v = 1;
    spd[e] = v;
  }
}

// LayerNorm: one 64-lane wave per node, 4 nodes per block
__global__ void k_ln(const float* __restrict__ in, const float* __restrict__ g,
                     const float* __restrict__ b, float* __restrict__ out){
  int node = blockIdx.x*4 + (threadIdx.x >> 6);
  int lane = threadIdx.x & 63;
  float4 v = ((const float4*)(in + (size_t)node*CC))[lane];
  float s  = v.x+v.y+v.z+v.w;
  float sq = v.x*v.x+v.y*v.y+v.z*v.z+v.w*v.w;
  #pragma unroll
  for(int m=32;m>=1;m>>=1){ s += __shfl_xor(s,m); sq += __shfl_xor(sq,m); }
  float mu  = s * (1.0f/CC);
  float var = sq * (1.0f/CC) - mu*mu;
  float inv = rsqrtf(var + 1e-5f);
  float4 gv = ((const float4*)g)[lane];
  float4 bv = ((const float4*)b)[lane];
  float4 o;
  o.x = gv.x*(v.x-mu)*inv + bv.x;
  o.y = gv.y*(v.y-mu)*inv + bv.y;
  o.z = gv.z*(v.z-mu)*inv + bv.z;
  o.w = gv.w*(v.w-mu)*inv + bv.w;
  ((float4*)(out + (size_t)node*CC))[lane] = o;
}

// C = A[M,K] @ B[K,Nc] + bias ; MODE 0: plain, 1: + add, 2: exact gelu
template<int MODE>
__global__ void k_gemm(const float* __restrict__ A, const float* __restrict__ B,
                       const float* __restrict__ bias, const float* __restrict__ add,
                       float* __restrict__ Cout, int M, int Nc, int K){
  __shared__ float As[16][68];
  __shared__ float Bs[16][68];
  int tid = threadIdx.x;
  int bm = blockIdx.y*64, bn = blockIdx.x*64;
  int tm = (tid>>4)<<2, tn = (tid&15)<<2;
  float acc[4][4] = {{0.f}};
  for(int k0=0;k0<K;k0+=16){
    #pragma unroll
    for(int j=0;j<4;j++){
      int idx = tid + j*256;
      int r = idx >> 4, c = idx & 15;
      As[c][r] = A[(size_t)(bm+r)*K + k0 + c];
    }
    #pragma unroll
    for(int j=0;j<4;j++){
      int idx = tid + j*256;
      int r = idx >> 6, c = idx & 63;
      Bs[r][c] = B[(size_t)(k0+r)*Nc + bn + c];
    }
    __syncthreads();
    #pragma unroll
    for(int kk=0;kk<16;kk++){
      float a[4], bb[4];
      a[0]=As[kk][tm]; a[1]=As[kk][tm+1]; a[2]=As[kk][tm+2]; a[3]=As[kk][tm+3];
      bb[0]=Bs[kk][tn]; bb[1]=Bs[kk][tn+1]; bb[2]=Bs[kk][tn+2]; bb[3]=Bs[kk][tn+3];
      #pragma unroll
      for(int i=0;i<4;i++)
        #pragma unroll
        for(int j=0;j<4;j++)
          acc[i][j] += a[i]*bb[j];
    }
    __syncthreads();
  }
  #pragma unroll
  for(int i=0;i<4;i++){
    int r = bm+tm+i;
    #pragma unroll
    for(int j=0;j<4;j++){
      int c = bn+tn+j;
      float v = acc[i][j] + bias[c];
      if(MODE==1) v += add[(size_t)r*Nc + c];
      if(MODE==2) v = 0.5f*v*(1.0f + erff(v*0.70710678118654752f));
      Cout[(size_t)r*Nc + c] = v;
    }
  }
}

// one block per edge; 8 heads x 32 lanes
__global__ void k_scores(const int* __restrict__ src, const int* __restrict__ dst,
                         const float* __restrict__ Q, const float* __restrict__ K,
                         const int* __restrict__ spd, const float* __restrict__ spde,
                         const float* __restrict__ etb, float* __restrict__ scores){
  int e = blockIdx.x;
  int t = threadIdx.x;
  int h = t >> 5, l = t & 31;
  int s = src[e], d = dst[e];
  float q = Q[(size_t)d*CC + h*DHD + l];
  float k = K[(size_t)s*CC + h*DHD + l];
  float v = q*k;
  #pragma unroll
  for(int mk=16;mk>=1;mk>>=1) v += __shfl_xor(v,mk);
  if(l==0)
    scores[(size_t)e*HH+h] = v*0.17677669529663687f + spde[spd[e]*HH+h] + etb[0];
}

__global__ void k_scan(const int* __restrict__ deg, int* __restrict__ offs){
  __shared__ int part[1024];
  int t = threadIdx.x;
  int v0=deg[t*4], v1=deg[t*4+1], v2=deg[t*4+2], v3=deg[t*4+3];
  int s = v0+v1+v2+v3;
  part[t] = s;
  __syncthreads();
  for(int d=1; d<1024; d<<=1){
    int x = (t>=d) ? part[t-d] : 0;
    __syncthreads();
    part[t] += x;
    __syncthreads();
  }
  int base = (t>0) ? part[t-1] : 0;
  offs[t*4]   = base;
  offs[t*4+1] = base+v0;
  offs[t*4+2] = base+v0+v1;
  offs[t*4+3] = base+v0+v1+v2;
  if(t==1023) offs[4096] = base+s;
}

__global__ void k_scatter(const int* __restrict__ dst, const int* __restrict__ offs,
                          int* __restrict__ cursor, int* __restrict__ elist){
  int e = blockIdx.x*256+threadIdx.x;
  if(e<EE){
    int d = dst[e];
    int p = atomicAdd(&cursor[d],1);
    elist[offs[d]+p] = e;
  }
}

// one block per dst node; 8 heads x 32 lanes (lane owns one DH element)
__global__ void k_agg(const int* __restrict__ src, const int* __restrict__ offs,
                      const int* __restrict__ elist, const float* __restrict__ scores,
                      const float* __restrict__ V, float* __restrict__ msg){
  int d = blockIdx.x;
  int t = threadIdx.x; int h = t>>5, l = t&31;
  int o0 = offs[d], deg = offs[d+1]-o0;
  float m = -3.0e38f;
  for(int i=l;i<deg;i+=32) m = fmaxf(m, scores[(size_t)elist[o0+i]*HH+h]);
  #pragma unroll
  for(int mk=16;mk>=1;mk>>=1) m = fmaxf(m, __shfl_xor(m,mk));
  float ssum = 0.f;
  for(int i=l;i<deg;i+=32) ssum += expf(scores[(size_t)elist[o0+i]*HH+h]-m);
  #pragma unroll
  for(int mk=16;mk>=1;mk>>=1) ssum += __shfl_xor(ssum,mk);
  float inv = (ssum>0.f) ? 1.f/ssum : 1.f;
  float acc = 0.f;
  for(int i=0;i<deg;i++){
    int e = elist[o0+i];
    float w = expf(scores[(size_t)e*HH+h]-m)*inv;
    acc += w * V[(size_t)src[e]*CC + h*DHD + l];
  }
  msg[(size_t)d*CC + h*DHD + l] = acc;
}

extern "C" void kernel_launch(void* const* d_in, const int* in_sizes, int n_in,
                              void* d_out, int out_size, void* d_ws, size_t ws_size,
                              hipStream_t stream){
  const float* x  = (const float*)d_in[0];
  const int*  ei  = (const int*)d_in[1];
  const float* Wq = (const float*)d_in[2];  const float* bq = (const float*)d_in[3];
  const float* Wk = (const float*)d_in[4];  const float* bk = (const float*)d_in[5];
  const float* Wv = (const float*)d_in[6];  const float* bv = (const float*)d_in[7];
  const float* Wo = (const float*)d_in[8];  const float* bo = (const float*)d_in[9];
  const float* W1 = (const float*)d_in[10]; const float* b1 = (const float*)d_in[11];
  const float* W2 = (const float*)d_in[12]; const float* b2 = (const float*)d_in[13];
  const float* g1 = (const float*)d_in[14]; const float* be1= (const float*)d_in[15];
  const float* g2 = (const float*)d_in[16]; const float* be2= (const float*)d_in[17];
  const float* spde = (const float*)d_in[18];
  const float* iemb = (const float*)d_in[19];
  const float* oemb = (const float*)d_in[20];
  const float* etb  = (const float*)d_in[21];
  const int* src = ei;
  const int* dst = ei + EE;
  float* out = (float*)d_out;

  const size_t NC = (size_t)NN*CC;
  float* ws   = (float*)d_ws;
  float* x_in = ws;
  float* hbuf = ws + 1*NC;
  float* hn   = ws + 2*NC;
  float* msg  = ws + 3*NC;
  float* xn   = ws + 4*NC;
  float* Qm   = ws + 5*NC;
  float* Km   = ws + 6*NC;
  float* Vm   = ws + 7*NC;
  float* ff1  = xn;  // reuse xn..Vm region (4*NC) after attention is done
  float* scores = ws + 8*NC;                       // EE*HH floats
  unsigned* F1 = (unsigned*)(scores + (size_t)EE*HH);
  unsigned* F2 = F1 + (size_t)NN*FW;
  unsigned* F3 = F2 + (size_t)NN*FW;
  int* spd    = (int*)(F3 + (size_t)NN*FW);
  int* indeg  = spd + EE;
  int* outdeg = indeg + NN;
  int* offs   = outdeg + NN;    // NN+1
  int* cursor = offs + NN + 1;
  int* elist  = cursor + NN;

  hipMemsetAsync(F1, 0, (size_t)3*NN*FW*4, stream);
  hipMemsetAsync(indeg, 0, (size_t)2*NN*4, stream);
  hipMemsetAsync(cursor, 0, (size_t)NN*4, stream);

  k_deg<<<EE/256,256,0,stream>>>(src,dst,indeg,outdeg);
  k_f1 <<<EE/256,256,0,stream>>>(src,dst,F1);
  k_prop<<<(EE*FW)/256,256,0,stream>>>(src,dst,F1,F2);
  k_prop<<<(EE*FW)/256,256,0,stream>>>(src,dst,F2,F3);
  k_spd<<<EE/256,256,0,stream>>>(src,dst,F1,F2,F3,spd);
  k_xin<<<NN,256,0,stream>>>(x,indeg,outdeg,iemb,oemb,x_in);
  k_ln <<<NN/4,256,0,stream>>>(x_in,g1,be1,xn);

  dim3 g64(CC/64, NN/64);
  k_gemm<0><<<g64,256,0,stream>>>(xn,Wq,bq,nullptr,Qm,NN,CC,CC);
  k_gemm<0><<<g64,256,0,stream>>>(xn,Wk,bk,nullptr,Km,NN,CC,CC);
  k_gemm<0><<<g64,256,0,stream>>>(xn,Wv,bv,nullptr,Vm,NN,CC,CC);

  k_scores<<<EE,256,0,stream>>>(src,dst,Qm,Km,spd,spde,etb,scores);
  k_scan<<<1,1024,0,stream>>>(indeg,offs);
  k_scatter<<<EE/256,256,0,stream>>>(dst,offs,cursor,elist);
  k_agg<<<NN,256,0,stream>>>(src,offs,elist,scores,Vm,msg);

  k_gemm<1><<<g64,256,0,stream>>>(msg,Wo,bo,x_in,hbuf,NN,CC,CC);
  k_ln <<<NN/4,256,0,stream>>>(hbuf,g2,be2,hn);
  dim3 g1k(1024/64, NN/64);
  k_gemm<2><<<g1k,256,0,stream>>>(hn,W1,b1,nullptr,ff1,NN,1024,CC);
  k_gemm<1><<<g64,256,0,stream>>>(ff1,W2,b2,hbuf,out,NN,CC,1024);
}

// Round 3
// 171.328 us; speedup vs baseline: 1.9053x; 1.9053x over previous
//
#include <hip/hip_runtime.h>
#include <math.h>

#define NN 4096
#define CC 256
#define HH 8
#define DHD 32
#define EE 32768
#define FW 128   // bitset words per row (4096/32)

typedef float f32x4 __attribute__((ext_vector_type(4)));
typedef __bf16 bf16x8 __attribute__((ext_vector_type(8)));
typedef __bf16 bf16x4 __attribute__((ext_vector_type(4)));

__device__ __forceinline__ int bucketf(int d){
  float l = log2f((float)d + 1.0f);
  int b = (int)floorf(l);
  return b < 0 ? 0 : (b > 8 ? 8 : b);
}

__global__ void k_deg(const int* __restrict__ src, const int* __restrict__ dst,
                      int* __restrict__ indeg, int* __restrict__ outdeg){
  int e = blockIdx.x*256 + threadIdx.x;
  if(e < EE){
    atomicAdd(&indeg[dst[e]], 1);
    atomicAdd(&outdeg[src[e]], 1);
  }
}

__global__ void k_xin(const float* __restrict__ x, const int* __restrict__ indeg,
                      const int* __restrict__ outdeg, const float* __restrict__ iemb,
                      const float* __restrict__ oemb, float* __restrict__ x_in){
  int n = blockIdx.x; int c = threadIdx.x;
  int bi = bucketf(indeg[n]);
  int bo = bucketf(outdeg[n]);
  x_in[n*CC+c] = x[n*CC+c] + iemb[bi*CC+c] + oemb[bo*CC+c];
}

__global__ void k_f1(const int* __restrict__ src, const int* __restrict__ dst,
                     unsigned* __restrict__ F1){
  int e = blockIdx.x*256 + threadIdx.x;
  if(e < EE){
    int s = src[e], d = dst[e];
    atomicOr(&F1[d*FW + (s>>5)], 1u << (s&31));
  }
}

__global__ void k_prop(const int* __restrict__ src, const int* __restrict__ dst,
                       const unsigned* __restrict__ Fin, unsigned* __restrict__ Fout){
  int id = blockIdx.x*256 + threadIdx.x;  // EE*FW threads
  int e = id >> 7, w = id & (FW-1);
  int s = src[e], d = dst[e];
  unsigned v = Fin[s*FW + w];
  if(v) atomicOr(&Fout[d*FW + w], v);
}

__global__ void k_spd(const int* __restrict__ src, const int* __restrict__ dst,
                      const unsigned* __restrict__ F1, const unsigned* __restrict__ F2,
                      const unsigned* __restrict__ F3, int* __restrict__ spd){
  int e = blockIdx.x*256 + threadIdx.x;
  if(e < EE){
    int s = src[e], d = dst[e];
    int wi = s*FW + (d>>5); unsigned b = 1u << (d&31);
    int v = 4;
    if (F3[wi] & b) v = 3;
    if (F2[wi] & b) v = 2;
    if (F1[wi] & b) v = 1;
    spd[e] = v;
  }
}

// LayerNorm: one 64-lane wave per node, 4 nodes per block; bf16 output
__global__ void k_ln(const float* __restrict__ in, const float* __restrict__ g,
                     const float* __restrict__ b, __bf16* __restrict__ out){
  int node = blockIdx.x*4 + (threadIdx.x >> 6);
  int lane = threadIdx.x & 63;
  float4 v = ((const float4*)(in + (size_t)node*CC))[lane];
  float s  = v.x+v.y+v.z+v.w;
  float sq = v.x*v.x+v.y*v.y+v.z*v.z+v.w*v.w;
  #pragma unroll
  for(int m=32;m>=1;m>>=1){ s += __shfl_xor(s,m); sq += __shfl_xor(sq,m); }
  float mu  = s * (1.0f/CC);
  float var = sq * (1.0f/CC) - mu*mu;
  float inv = rsqrtf(var + 1e-5f);
  float4 gv = ((const float4*)g)[lane];
  float4 bv = ((const float4*)b)[lane];
  bf16x4 o;
  o[0] = (__bf16)(gv.x*(v.x-mu)*inv + bv.x);
  o[1] = (__bf16)(gv.y*(v.y-mu)*inv + bv.y);
  o[2] = (__bf16)(gv.z*(v.z-mu)*inv + bv.z);
  o[3] = (__bf16)(gv.w*(v.w-mu)*inv + bv.w);
  *(bf16x4*)(out + (size_t)node*CC + lane*4) = o;
}

// weight transpose + bf16 cast: W [K,N] fp32 -> Wt [N,K] bf16
__global__ void k_tr(const float* __restrict__ W, __bf16* __restrict__ Wt, int K, int N){
  int id = blockIdx.x*256 + threadIdx.x;
  int n = id / K, k = id - n*K;
  Wt[id] = (__bf16)W[(size_t)k*N + n];
}

// bf16 MFMA GEMM: C[M,N] = A[M,K] @ Bt[N,K]^T + bias (+add) (gelu->bf16)
// 64x64 tile, BK=64, 4 waves (2x2), XOR-swizzled LDS
template<int MODE>
__global__ __launch_bounds__(256) void k_bgemm(const __bf16* __restrict__ A, const __bf16* __restrict__ Bt,
                       const float* __restrict__ bias, const float* __restrict__ add,
                       float* __restrict__ outf, __bf16* __restrict__ outb,
                       int M, int N, int K){
  __shared__ __bf16 As[64*64];
  __shared__ __bf16 Bs[64*64];
  const int tid = threadIdx.x;
  const int lane = tid & 63, w = tid >> 6;
  const int wr = w >> 1, wc = w & 1;
  const int l15 = lane & 15, g = lane >> 4;
  const int bm = blockIdx.y*64, bn = blockIdx.x*64;
  f32x4 acc[2][2] = {};
  for(int k0=0; k0<K; k0+=64){
    #pragma unroll
    for(int rep=0; rep<2; rep++){
      int q = tid + rep*256;
      int row = q>>3, cb = (q&7)*16;
      int byte_ = row*128 + cb; byte_ ^= (row&7)<<4;
      *(bf16x8*)((char*)As + byte_) = *(const bf16x8*)(A  + (size_t)(bm+row)*K + k0 + (q&7)*8);
      *(bf16x8*)((char*)Bs + byte_) = *(const bf16x8*)(Bt + (size_t)(bn+row)*K + k0 + (q&7)*8);
    }
    __syncthreads();
    #pragma unroll
    for(int ks=0; ks<2; ks++){
      bf16x8 a[2], b[2];
      #pragma unroll
      for(int i=0;i<2;i++){
        int row = wr*32 + i*16 + l15;
        int byte_ = row*128 + ks*64 + g*16; byte_ ^= (row&7)<<4;
        a[i] = *(const bf16x8*)((const char*)As + byte_);
      }
      #pragma unroll
      for(int j=0;j<2;j++){
        int row = wc*32 + j*16 + l15;
        int byte_ = row*128 + ks*64 + g*16; byte_ ^= (row&7)<<4;
        b[j] = *(const bf16x8*)((const char*)Bs + byte_);
      }
      #pragma unroll
      for(int i=0;i<2;i++)
        #pragma unroll
        for(int j=0;j<2;j++)
          acc[i][j] = __builtin_amdgcn_mfma_f32_16x16x32_bf16(a[i], b[j], acc[i][j], 0, 0, 0);
    }
    __syncthreads();
  }
  #pragma unroll
  for(int i=0;i<2;i++){
    #pragma unroll
    for(int j=0;j<2;j++){
      int col = bn + wc*32 + j*16 + l15;
      float bv = bias[col];
      #pragma unroll
      for(int r=0;r<4;r++){
        int rowg = bm + wr*32 + i*16 + g*4 + r;
        float v = acc[i][j][r] + bv;
        if(MODE==1) v += add[(size_t)rowg*N + col];
        if(MODE==2){
          v = 0.5f*v*(1.0f + erff(v*0.70710678118654752f));
          outb[(size_t)rowg*N + col] = (__bf16)v;
        } else {
          outf[(size_t)rowg*N + col] = v;
        }
      }
    }
  }
}

// one block per edge; 8 heads x 32 lanes. QKV fused buffer [N][768]
__global__ void k_scores(const int* __restrict__ src, const int* __restrict__ dst,
                         const float* __restrict__ QKV,
                         const int* __restrict__ spd, const float* __restrict__ spde,
                         const float* __restrict__ etb, float* __restrict__ scores){
  int e = blockIdx.x;
  int t = threadIdx.x;
  int h = t >> 5, l = t & 31;
  int s = src[e], d = dst[e];
  float q = QKV[(size_t)d*768 + h*DHD + l];
  float k = QKV[(size_t)s*768 + 256 + h*DHD + l];
  float v = q*k;
  #pragma unroll
  for(int mk=16;mk>=1;mk>>=1) v += __shfl_xor(v,mk);
  if(l==0)
    scores[(size_t)e*HH+h] = v*0.17677669529663687f + spde[spd[e]*HH+h] + etb[0];
}

__global__ void k_scan(const int* __restrict__ deg, int* __restrict__ offs){
  __shared__ int part[1024];
  int t = threadIdx.x;
  int v0=deg[t*4], v1=deg[t*4+1], v2=deg[t*4+2], v3=deg[t*4+3];
  int s = v0+v1+v2+v3;
  part[t] = s;
  __syncthreads();
  for(int d=1; d<1024; d<<=1){
    int x = (t>=d) ? part[t-d] : 0;
    __syncthreads();
    part[t] += x;
    __syncthreads();
  }
  int base = (t>0) ? part[t-1] : 0;
  offs[t*4]   = base;
  offs[t*4+1] = base+v0;
  offs[t*4+2] = base+v0+v1;
  offs[t*4+3] = base+v0+v1+v2;
  if(t==1023) offs[4096] = base+s;
}

__global__ void k_scatter(const int* __restrict__ dst, const int* __restrict__ offs,
                          int* __restrict__ cursor, int* __restrict__ elist){
  int e = blockIdx.x*256+threadIdx.x;
  if(e<EE){
    int d = dst[e];
    int p = atomicAdd(&cursor[d],1);
    elist[offs[d]+p] = e;
  }
}

// one block per dst node; 8 heads x 32 lanes; V from QKV buffer; bf16 msg out
__global__ void k_agg(const int* __restrict__ src, const int* __restrict__ offs,
                      const int* __restrict__ elist, const float* __restrict__ scores,
                      const float* __restrict__ QKV, __bf16* __restrict__ msg){
  int d = blockIdx.x;
  int t = threadIdx.x; int h = t>>5, l = t&31;
  int o0 = offs[d], deg = offs[d+1]-o0;
  float m = -3.0e38f;
  for(int i=l;i<deg;i+=32) m = fmaxf(m, scores[(size_t)elist[o0+i]*HH+h]);
  #pragma unroll
  for(int mk=16;mk>=1;mk>>=1) m = fmaxf(m, __shfl_xor(m,mk));
  float ssum = 0.f;
  for(int i=l;i<deg;i+=32) ssum += expf(scores[(size_t)elist[o0+i]*HH+h]-m);
  #pragma unroll
  for(int mk=16;mk>=1;mk>>=1) ssum += __shfl_xor(ssum,mk);
  float inv = (ssum>0.f) ? 1.f/ssum : 1.f;
  float acc = 0.f;
  for(int i=0;i<deg;i++){
    int e = elist[o0+i];
    float wv = expf(scores[(size_t)e*HH+h]-m)*inv;
    acc += wv * QKV[(size_t)src[e]*768 + 512 + h*DHD + l];
  }
  msg[(size_t)d*CC + h*DHD + l] = (__bf16)acc;
}

extern "C" void kernel_launch(void* const* d_in, const int* in_sizes, int n_in,
                              void* d_out, int out_size, void* d_ws, size_t ws_size,
                              hipStream_t stream){
  const float* x  = (const float*)d_in[0];
  const int*  ei  = (const int*)d_in[1];
  const float* Wq = (const float*)d_in[2];  const float* bq = (const float*)d_in[3];
  const float* Wk = (const float*)d_in[4];  const float* bk = (const float*)d_in[5];
  const float* Wv = (const float*)d_in[6];  const float* bv = (const float*)d_in[7];
  const float* Wo = (const float*)d_in[8];  const float* bo = (const float*)d_in[9];
  const float* W1 = (const float*)d_in[10]; const float* b1 = (const float*)d_in[11];
  const float* W2 = (const float*)d_in[12]; const float* b2 = (const float*)d_in[13];
  const float* g1 = (const float*)d_in[14]; const float* be1= (const float*)d_in[15];
  const float* g2 = (const float*)d_in[16]; const float* be2= (const float*)d_in[17];
  const float* spde = (const float*)d_in[18];
  const float* iemb = (const float*)d_in[19];
  const float* oemb = (const float*)d_in[20];
  const float* etb  = (const float*)d_in[21];
  const int* src = ei;
  const int* dst = ei + EE;
  float* out = (float*)d_out;

  const size_t NC = (size_t)NN*CC;       // 1,048,576 floats
  float* ws   = (float*)d_ws;
  float* x_in = ws;                       // NC
  float* hbuf = ws + NC;                  // NC
  float* R    = ws + 2*NC;                // 3*NC region, multi-use:
  unsigned* F1 = (unsigned*)R;            //  early: F1,F2,F3 bitsets (1.5*NC)
  unsigned* F2 = F1 + (size_t)NN*FW;
  unsigned* F3 = F2 + (size_t)NN*FW;
  float* QKV   = R;                       //  mid:   QKV fp32 [NN][768] (3*NC)
  __bf16* ff1_bf = (__bf16*)R;            //  late:  ff1 bf16 [NN][1024] (2*NC)
  __bf16* hn_bf  = (__bf16*)(R + 2*NC);   //  late:  hn bf16 [NN][256] (0.5*NC)
  float* scores = ws + 5*NC;              // EE*HH = 262144 floats
  __bf16* xn_bf  = (__bf16*)(ws + 5*NC + 262144);   // NC bf16 = 524288 floats
  __bf16* msg_bf = (__bf16*)(ws + 5*NC + 786432);   // NC bf16 = 524288 floats
  __bf16* WqkvT = (__bf16*)(ws + 5*NC + 1310720);   // 196608 bf16
  __bf16* WoT   = WqkvT + 196608;                   // 65536
  __bf16* W1T   = WoT + 65536;                      // 262144
  __bf16* W2T   = W1T + 262144;                     // 262144
  float* bqkv   = ws + 5*NC + 1310720 + 393216;     // 768 floats
  int* spd    = (int*)(bqkv + 768);
  int* indeg  = spd + EE;
  int* outdeg = indeg + NN;
  int* offs   = outdeg + NN;    // NN+1
  int* cursor = offs + NN + 1;
  int* elist  = cursor + NN;

  (void)hipMemsetAsync(F1, 0, (size_t)3*NN*FW*4, stream);
  (void)hipMemsetAsync(indeg, 0, (size_t)2*NN*4, stream);
  (void)hipMemsetAsync(cursor, 0, (size_t)NN*4, stream);

  // weight prep (bf16 transpose) + bias concat
  k_tr<<<(256*256)/256,256,0,stream>>>(Wq, WqkvT,         256, 256);
  k_tr<<<(256*256)/256,256,0,stream>>>(Wk, WqkvT+65536,   256, 256);
  k_tr<<<(256*256)/256,256,0,stream>>>(Wv, WqkvT+131072,  256, 256);
  k_tr<<<(256*256)/256,256,0,stream>>>(Wo, WoT, 256, 256);
  k_tr<<<(256*1024)/256,256,0,stream>>>(W1, W1T, 256, 1024);
  k_tr<<<(1024*256)/256,256,0,stream>>>(W2, W2T, 1024, 256);
  (void)hipMemcpyAsync(bqkv,     bq, 256*4, hipMemcpyDeviceToDevice, stream);
  (void)hipMemcpyAsync(bqkv+256, bk, 256*4, hipMemcpyDeviceToDevice, stream);
  (void)hipMemcpyAsync(bqkv+512, bv, 256*4, hipMemcpyDeviceToDevice, stream);

  // graph structure
  k_deg<<<EE/256,256,0,stream>>>(src,dst,indeg,outdeg);
  k_f1 <<<EE/256,256,0,stream>>>(src,dst,F1);
  k_prop<<<(EE*FW)/256,256,0,stream>>>(src,dst,F1,F2);
  k_prop<<<(EE*FW)/256,256,0,stream>>>(src,dst,F2,F3);
  k_spd<<<EE/256,256,0,stream>>>(src,dst,F1,F2,F3,spd);
  k_xin<<<NN,256,0,stream>>>(x,indeg,outdeg,iemb,oemb,x_in);
  k_ln <<<NN/4,256,0,stream>>>(x_in,g1,be1,xn_bf);

  // QKV fused GEMM: [4096,768] = xn @ [Wq|Wk|Wv]
  dim3 gq(768/64, NN/64);
  k_bgemm<0><<<gq,256,0,stream>>>(xn_bf, WqkvT, bqkv, nullptr, QKV, nullptr, NN, 768, 256);

  k_scores<<<EE,256,0,stream>>>(src,dst,QKV,spd,spde,etb,scores);
  k_scan<<<1,1024,0,stream>>>(indeg,offs);
  k_scatter<<<EE/256,256,0,stream>>>(dst,offs,cursor,elist);
  k_agg<<<NN,256,0,stream>>>(src,offs,elist,scores,QKV,msg_bf);

  dim3 go(256/64, NN/64);
  k_bgemm<1><<<go,256,0,stream>>>(msg_bf, WoT, bo, x_in, hbuf, nullptr, NN, 256, 256);
  k_ln <<<NN/4,256,0,stream>>>(hbuf,g2,be2,hn_bf);
  dim3 gf1(1024/64, NN/64);
  k_bgemm<2><<<gf1,256,0,stream>>>(hn_bf, W1T, b1, nullptr, nullptr, ff1_bf, NN, 1024, 256);
  dim3 gf2(256/64, NN/64);
  k_bgemm<1><<<gf2,256,0,stream>>>(ff1_bf, W2T, b2, hbuf, out, nullptr, NN, 256, 1024);
}

// Round 5
// 107.384 us; speedup vs baseline: 3.0398x; 1.5955x over previous
//
#include <hip/hip_runtime.h>
#include <math.h>

#define NN 4096
#define CC 256
#define HH 8
#define DHD 32
#define EE 32768
#define FW 128   // bitset words per row (4096/32)

typedef float f32x4 __attribute__((ext_vector_type(4)));
typedef __bf16 bf16x8 __attribute__((ext_vector_type(8)));
typedef __bf16 bf16x4 __attribute__((ext_vector_type(4)));

__device__ __forceinline__ int bucketf(int d){
  float l = log2f((float)d + 1.0f);
  int b = (int)floorf(l);
  return b < 0 ? 0 : (b > 8 ? 8 : b);
}

__global__ void k_deg(const int* __restrict__ src, const int* __restrict__ dst,
                      int* __restrict__ indeg, int* __restrict__ outdeg){
  int e = blockIdx.x*256 + threadIdx.x;
  if(e < EE){
    atomicAdd(&indeg[dst[e]], 1);
    atomicAdd(&outdeg[src[e]], 1);
  }
}

__global__ void k_scan(const int* __restrict__ deg, int* __restrict__ offs){
  __shared__ int part[1024];
  int t = threadIdx.x;
  int v0=deg[t*4], v1=deg[t*4+1], v2=deg[t*4+2], v3=deg[t*4+3];
  int s = v0+v1+v2+v3;
  part[t] = s;
  __syncthreads();
  for(int d=1; d<1024; d<<=1){
    int x = (t>=d) ? part[t-d] : 0;
    __syncthreads();
    part[t] += x;
    __syncthreads();
  }
  int base = (t>0) ? part[t-1] : 0;
  offs[t*4]   = base;
  offs[t*4+1] = base+v0;
  offs[t*4+2] = base+v0+v1;
  offs[t*4+3] = base+v0+v1+v2;
  if(t==1023) offs[4096] = base+s;
}

// scatter edges by dst + build F1 bitset
__global__ void k_scatter(const int* __restrict__ src, const int* __restrict__ dst,
                          const int* __restrict__ offs, int* __restrict__ cursor,
                          int* __restrict__ elist, int* __restrict__ nsrc,
                          unsigned* __restrict__ F1){
  int e = blockIdx.x*256+threadIdx.x;
  if(e<EE){
    int d = dst[e], s = src[e];
    int p = atomicAdd(&cursor[d],1);
    int pos = offs[d]+p;
    elist[pos] = e;
    nsrc[pos]  = s;
    atomicOr(&F1[d*FW + (s>>5)], 1u << (s&31));
  }
}

// CSR propagation: Fout[d] = OR over in-neighbors s of Fin[s]. No atomics.
__global__ void k_prop(const int* __restrict__ offs, const int* __restrict__ nsrc,
                       const unsigned* __restrict__ Fin, unsigned* __restrict__ Fout){
  int d = blockIdx.x; int w = threadIdx.x;  // 128 threads = 1 word each
  int o0 = offs[d], o1 = offs[d+1];
  unsigned v = 0;
  for(int i=o0;i<o1;i++){
    int s = nsrc[i];
    v |= Fin[(size_t)s*FW + w];
  }
  Fout[(size_t)d*FW + w] = v;
}

// fused: x_in = x + deg-bucket embeds ; xn = LN(x_in). one wave per node.
__global__ void k_xin_ln(const float* __restrict__ x, const int* __restrict__ indeg,
                         const int* __restrict__ outdeg, const float* __restrict__ iemb,
                         const float* __restrict__ oemb, const float* __restrict__ g,
                         const float* __restrict__ b, float* __restrict__ x_in,
                         __bf16* __restrict__ xn){
  int node = blockIdx.x*4 + (threadIdx.x >> 6);
  int lane = threadIdx.x & 63;
  int bi = bucketf(indeg[node]);
  int bo = bucketf(outdeg[node]);
  float4 xv = ((const float4*)(x + (size_t)node*CC))[lane];
  float4 iv = ((const float4*)(iemb + (size_t)bi*CC))[lane];
  float4 ov = ((const float4*)(oemb + (size_t)bo*CC))[lane];
  float4 v;
  v.x = xv.x+iv.x+ov.x; v.y = xv.y+iv.y+ov.y;
  v.z = xv.z+iv.z+ov.z; v.w = xv.w+iv.w+ov.w;
  ((float4*)(x_in + (size_t)node*CC))[lane] = v;
  float s  = v.x+v.y+v.z+v.w;
  float sq = v.x*v.x+v.y*v.y+v.z*v.z+v.w*v.w;
  #pragma unroll
  for(int m=32;m>=1;m>>=1){ s += __shfl_xor(s,m); sq += __shfl_xor(sq,m); }
  float mu  = s * (1.0f/CC);
  float var = sq * (1.0f/CC) - mu*mu;
  float inv = rsqrtf(var + 1e-5f);
  float4 gv = ((const float4*)g)[lane];
  float4 bv = ((const float4*)b)[lane];
  bf16x4 o;
  o[0] = (__bf16)(gv.x*(v.x-mu)*inv + bv.x);
  o[1] = (__bf16)(gv.y*(v.y-mu)*inv + bv.y);
  o[2] = (__bf16)(gv.z*(v.z-mu)*inv + bv.z);
  o[3] = (__bf16)(gv.w*(v.w-mu)*inv + bv.w);
  *(bf16x4*)(xn + (size_t)node*CC + lane*4) = o;
}

// LayerNorm (fp32 in, bf16 out): one wave per node
__global__ void k_ln(const float* __restrict__ in, const float* __restrict__ g,
                     const float* __restrict__ b, __bf16* __restrict__ out){
  int node = blockIdx.x*4 + (threadIdx.x >> 6);
  int lane = threadIdx.x & 63;
  float4 v = ((const float4*)(in + (size_t)node*CC))[lane];
  float s  = v.x+v.y+v.z+v.w;
  float sq = v.x*v.x+v.y*v.y+v.z*v.z+v.w*v.w;
  #pragma unroll
  for(int m=32;m>=1;m>>=1){ s += __shfl_xor(s,m); sq += __shfl_xor(sq,m); }
  float mu  = s * (1.0f/CC);
  float var = sq * (1.0f/CC) - mu*mu;
  float inv = rsqrtf(var + 1e-5f);
  float4 gv = ((const float4*)g)[lane];
  float4 bv = ((const float4*)b)[lane];
  bf16x4 o;
  o[0] = (__bf16)(gv.x*(v.x-mu)*inv + bv.x);
  o[1] = (__bf16)(gv.y*(v.y-mu)*inv + bv.y);
  o[2] = (__bf16)(gv.z*(v.z-mu)*inv + bv.z);
  o[3] = (__bf16)(gv.w*(v.w-mu)*inv + bv.w);
  *(bf16x4*)(out + (size_t)node*CC + lane*4) = o;
}

// all weight transposes (fp32 [K,N] -> bf16 [N,K]) in one launch, LDS-tiled,
// plus the qkv bias concat. block tile map: Wq 0-15, Wk 16-31, Wv 32-47,
// Wo 48-63, W1 64-127, W2 128-191, bias 192.
__global__ void k_trall(const float* __restrict__ Wq, const float* __restrict__ Wk,
                        const float* __restrict__ Wv, const float* __restrict__ Wo,
                        const float* __restrict__ W1, const float* __restrict__ W2,
                        const float* __restrict__ bq, const float* __restrict__ bk,
                        const float* __restrict__ bv,
                        __bf16* __restrict__ WqkvT, __bf16* __restrict__ WoT,
                        __bf16* __restrict__ W1T, __bf16* __restrict__ W2T,
                        float* __restrict__ bqkv){
  int b = blockIdx.x;
  int tid = threadIdx.x;
  if(b == 192){
    if(tid < 256){
      bqkv[tid]     = bq[tid];
      bqkv[256+tid] = bk[tid];
      bqkv[512+tid] = bv[tid];
    }
    return;
  }
  const float* W; __bf16* Wt; int K, N, tile;
  if(b < 16)      { W=Wq; Wt=WqkvT;        K=256;  N=256;  tile=b; }
  else if(b < 32) { W=Wk; Wt=WqkvT+65536;  K=256;  N=256;  tile=b-16; }
  else if(b < 48) { W=Wv; Wt=WqkvT+131072; K=256;  N=256;  tile=b-32; }
  else if(b < 64) { W=Wo; Wt=WoT;          K=256;  N=256;  tile=b-48; }
  else if(b < 128){ W=W1; Wt=W1T;          K=256;  N=1024; tile=b-64; }
  else            { W=W2; Wt=W2T;          K=1024; N=256;  tile=b-128; }
  int nK = K/64;
  int tk = tile % nK, tn = tile / nK;
  __shared__ float T[64][65];
  int c = tid & 63, r0 = tid >> 6;
  #pragma unroll
  for(int i=0;i<16;i++){
    int row = r0*16 + i;
    T[row][c] = W[(size_t)(tk*64+row)*N + tn*64 + c];
  }
  __syncthreads();
  #pragma unroll
  for(int i=0;i<16;i++){
    int row = r0*16 + i;
    Wt[(size_t)(tn*64+row)*K + tk*64 + c] = (__bf16)T[c][row];
  }
}

// bf16 MFMA GEMM: C[M,N] = A[M,K] @ Bt[N,K]^T + bias
// MODE 0: fp32 out, 1: fp32 out + add, 2: gelu -> bf16 out, 3: bf16 out
template<int MODE>
__global__ __launch_bounds__(256) void k_bgemm(const __bf16* __restrict__ A, const __bf16* __restrict__ Bt,
                       const float* __restrict__ bias, const float* __restrict__ add,
                       float* __restrict__ outf, __bf16* __restrict__ outb,
                       int M, int N, int K){
  __shared__ __bf16 As[64*64];
  __shared__ __bf16 Bs[64*64];
  const int tid = threadIdx.x;
  const int lane = tid & 63, w = tid >> 6;
  const int wr = w >> 1, wc = w & 1;
  const int l15 = lane & 15, g = lane >> 4;
  const int bm = blockIdx.y*64, bn = blockIdx.x*64;
  f32x4 acc[2][2] = {};
  for(int k0=0; k0<K; k0+=64){
    #pragma unroll
    for(int rep=0; rep<2; rep++){
      int q = tid + rep*256;
      int row = q>>3, cb = (q&7)*16;
      int byte_ = row*128 + cb; byte_ ^= (row&7)<<4;
      *(bf16x8*)((char*)As + byte_) = *(const bf16x8*)(A  + (size_t)(bm+row)*K + k0 + (q&7)*8);
      *(bf16x8*)((char*)Bs + byte_) = *(const bf16x8*)(Bt + (size_t)(bn+row)*K + k0 + (q&7)*8);
    }
    __syncthreads();
    #pragma unroll
    for(int ks=0; ks<2; ks++){
      bf16x8 a[2], b[2];
      #pragma unroll
      for(int i=0;i<2;i++){
        int row = wr*32 + i*16 + l15;
        int byte_ = row*128 + ks*64 + g*16; byte_ ^= (row&7)<<4;
        a[i] = *(const bf16x8*)((const char*)As + byte_);
      }
      #pragma unroll
      for(int j=0;j<2;j++){
        int row = wc*32 + j*16 + l15;
        int byte_ = row*128 + ks*64 + g*16; byte_ ^= (row&7)<<4;
        b[j] = *(const bf16x8*)((const char*)Bs + byte_);
      }
      #pragma unroll
      for(int i=0;i<2;i++)
        #pragma unroll
        for(int j=0;j<2;j++)
          acc[i][j] = __builtin_amdgcn_mfma_f32_16x16x32_bf16(a[i], b[j], acc[i][j], 0, 0, 0);
    }
    __syncthreads();
  }
  #pragma unroll
  for(int i=0;i<2;i++){
    #pragma unroll
    for(int j=0;j<2;j++){
      int col = bn + wc*32 + j*16 + l15;
      float bv = bias[col];
      #pragma unroll
      for(int r=0;r<4;r++){
        int rowg = bm + wr*32 + i*16 + g*4 + r;
        float v = acc[i][j][r] + bv;
        if(MODE==1) v += add[(size_t)rowg*N + col];
        if(MODE==2){
          v = 0.5f*v*(1.0f + erff(v*0.70710678118654752f));
          outb[(size_t)rowg*N + col] = (__bf16)v;
        } else if(MODE==3){
          outb[(size_t)rowg*N + col] = (__bf16)v;
        } else {
          outf[(size_t)rowg*N + col] = v;
        }
      }
    }
  }
}

// 4 edges per block, one wave per edge (2 heads x 32 lanes per pass, 4 passes).
// spd probe inlined.
__global__ void k_scores(const int* __restrict__ src, const int* __restrict__ dst,
                         const __bf16* __restrict__ QKV,
                         const unsigned* __restrict__ F1, const unsigned* __restrict__ F2,
                         const unsigned* __restrict__ F3,
                         const float* __restrict__ spde, const float* __restrict__ etb,
                         float* __restrict__ scores){
  int e = blockIdx.x*4 + (threadIdx.x>>6);
  int l = threadIdx.x & 63;
  int c = l & 31;
  int s = src[e], d = dst[e];
  float acc[4];
  #pragma unroll
  for(int p=0;p<4;p++){
    int h = p*2 + (l>>5);
    float q = (float)QKV[(size_t)d*768 + h*DHD + c];
    float k = (float)QKV[(size_t)s*768 + 256 + h*DHD + c];
    float v = q*k;
    #pragma unroll
    for(int mk=16;mk>=1;mk>>=1) v += __shfl_xor(v,mk);
    acc[p] = v;
  }
  if(c==0){
    size_t wi = (size_t)s*FW + (d>>5); unsigned bb = 1u << (d&31);
    int sp = 4;
    if(F3[wi] & bb) sp = 3;
    if(F2[wi] & bb) sp = 2;
    if(F1[wi] & bb) sp = 1;
    float base = etb[0];
    #pragma unroll
    for(int p=0;p<4;p++){
      int h = p*2 + (l>>5);
      scores[(size_t)e*HH+h] = acc[p]*0.17677669529663687f + spde[sp*HH+h] + base;
    }
  }
}

// one block per dst node; 8 heads x 32 lanes; V bf16 from QKV; bf16 msg out
__global__ void k_agg(const int* __restrict__ nsrc, const int* __restrict__ offs,
                      const int* __restrict__ elist, const float* __restrict__ scores,
                      const __bf16* __restrict__ QKV, __bf16* __restrict__ msg){
  int d = blockIdx.x;
  int t = threadIdx.x; int h = t>>5, l = t&31;
  int o0 = offs[d], deg = offs[d+1]-o0;
  float m = -3.0e38f;
  for(int i=l;i<deg;i+=32) m = fmaxf(m, scores[(size_t)elist[o0+i]*HH+h]);
  #pragma unroll
  for(int mk=16;mk>=1;mk>>=1) m = fmaxf(m, __shfl_xor(m,mk));
  float ssum = 0.f;
  for(int i=l;i<deg;i+=32) ssum += expf(scores[(size_t)elist[o0+i]*HH+h]-m);
  #pragma unroll
  for(int mk=16;mk>=1;mk>>=1) ssum += __shfl_xor(ssum,mk);
  float inv = (ssum>0.f) ? 1.f/ssum : 1.f;
  float acc = 0.f;
  for(int i=0;i<deg;i++){
    int e = elist[o0+i];
    int s = nsrc[o0+i];
    float wv = expf(scores[(size_t)e*HH+h]-m)*inv;
    acc += wv * (float)QKV[(size_t)s*768 + 512 + h*DHD + l];
  }
  msg[(size_t)d*CC + h*DHD + l] = (__bf16)acc;
}

extern "C" void kernel_launch(void* const* d_in, const int* in_sizes, int n_in,
                              void* d_out, int out_size, void* d_ws, size_t ws_size,
                              hipStream_t stream){
  const float* x  = (const float*)d_in[0];
  const int*  ei  = (const int*)d_in[1];
  const float* Wq = (const float*)d_in[2];  const float* bq = (const float*)d_in[3];
  const float* Wk = (const float*)d_in[4];  const float* bk = (const float*)d_in[5];
  const float* Wv = (const float*)d_in[6];  const float* bv = (const float*)d_in[7];
  const float* Wo = (const float*)d_in[8];  const float* bo = (const float*)d_in[9];
  const float* W1 = (const float*)d_in[10]; const float* b1 = (const float*)d_in[11];
  const float* W2 = (const float*)d_in[12]; const float* b2 = (const float*)d_in[13];
  const float* g1 = (const float*)d_in[14]; const float* be1= (const float*)d_in[15];
  const float* g2 = (const float*)d_in[16]; const float* be2= (const float*)d_in[17];
  const float* spde = (const float*)d_in[18];
  const float* iemb = (const float*)d_in[19];
  const float* oemb = (const float*)d_in[20];
  const float* etb  = (const float*)d_in[21];
  const int* src = ei;
  const int* dst = ei + EE;
  float* out = (float*)d_out;

  const size_t NC = (size_t)NN*CC;       // 1,048,576 floats
  float* ws   = (float*)d_ws;
  // ---- layout in float words (explicit, non-overlapping among live ranges) ----
  float* x_in = ws;                                   // [0, NC)
  float* hbuf = ws + NC;                              // [NC, 2NC)
  int* indeg  = (int*)(ws + 2*NC);                    // 2NC + [0,4096)
  int* outdeg = indeg + NN;                           // +4096
  int* cursor = outdeg + NN;                          // +4096  (zeroed block: 12288+F1)
  unsigned* F1 = (unsigned*)(cursor + NN);            // 2NC+12288, 524288 words
  unsigned* F2 = F1 + (size_t)NN*FW;                  // +524288
  unsigned* F3 = F2 + (size_t)NN*FW;                  // ends at word 3,682,304
  __bf16* QKV  = (__bf16*)(F3 + (size_t)NN*FW);       // [3,682,304 , 5,255,168) words
  float* scores = ws + 5255168;                       // 262,144 words
  __bf16* xn_bf  = (__bf16*)(ws + 5517312);           // 524,288 words
  __bf16* msg_bf = (__bf16*)(ws + 6041600);           // 524,288 words
  __bf16* WqkvT  = (__bf16*)(ws + 6565888);           // 98,304 words
  __bf16* WoT    = WqkvT + 196608;                    // 32,768 words
  __bf16* W1T    = WoT + 65536;                       // 131,072 words
  __bf16* W2T    = W1T + 262144;                      // 131,072 words -> ends 6,959,104
  float* bqkv    = ws + 6959104;                      // 768
  int* offs      = (int*)(bqkv + 768);                // 4097 (+pad)
  int* elist     = offs + NN + 4;                     // EE
  int* nsrc      = elist + EE;                        // EE  -> ends ~7,029,512 words (28.1 MB)
  // late-phase reuse (regions dead after k_scores/k_agg):
  __bf16* ff1_bf = (__bf16*)(ws + 2*NC);              // [2NC,4NC): over F1-F3 (dead)
  __bf16* hn_bf  = (__bf16*)(ws + 4*NC);              // [4NC,4.5NC): over QKV tail (dead)

  // single memset: indeg/outdeg/cursor + F1
  (void)hipMemsetAsync(indeg, 0, (size_t)(3*NN + NN*FW)*4, stream);

  k_trall<<<193,256,0,stream>>>(Wq,Wk,Wv,Wo,W1,W2,bq,bk,bv,WqkvT,WoT,W1T,W2T,bqkv);
  k_deg<<<EE/256,256,0,stream>>>(src,dst,indeg,outdeg);
  k_scan<<<1,1024,0,stream>>>(indeg,offs);
  k_scatter<<<EE/256,256,0,stream>>>(src,dst,offs,cursor,elist,nsrc,F1);
  k_prop<<<NN,FW,0,stream>>>(offs,nsrc,F1,F2);
  k_prop<<<NN,FW,0,stream>>>(offs,nsrc,F2,F3);
  k_xin_ln<<<NN/4,256,0,stream>>>(x,indeg,outdeg,iemb,oemb,g1,be1,x_in,xn_bf);

  // QKV fused GEMM: [4096,768] bf16 = xn @ [Wq|Wk|Wv]
  dim3 gq(768/64, NN/64);
  k_bgemm<3><<<gq,256,0,stream>>>(xn_bf, WqkvT, bqkv, nullptr, nullptr, QKV, NN, 768, 256);

  k_scores<<<EE/4,256,0,stream>>>(src,dst,QKV,F1,F2,F3,spde,etb,scores);
  k_agg<<<NN,256,0,stream>>>(nsrc,offs,elist,scores,QKV,msg_bf);

  dim3 go(256/64, NN/64);
  k_bgemm<1><<<go,256,0,stream>>>(msg_bf, WoT, bo, x_in, hbuf, nullptr, NN, 256, 256);
  k_ln <<<NN/4,256,0,stream>>>(hbuf,g2,be2,hn_bf);
  dim3 gf1(1024/64, NN/64);
  k_bgemm<2><<<gf1,256,0,stream>>>(hn_bf, W1T, b1, nullptr, nullptr, ff1_bf, NN, 1024, 256);
  dim3 gf2(256/64, NN/64);
  k_bgemm<1><<<gf2,256,0,stream>>>(ff1_bf, W2T, b2, hbuf, out, nullptr, NN, 256, 1024);
}

// Round 6
// 106.932 us; speedup vs baseline: 3.0526x; 1.0042x over previous
//
#include <hip/hip_runtime.h>
#include <math.h>

#define NN 4096
#define CC 256
#define HH 8
#define DHD 32
#define EE 32768
#define FW 128   // bitset words per row (4096/32)

typedef float f32x4 __attribute__((ext_vector_type(4)));
typedef __bf16 bf16x8 __attribute__((ext_vector_type(8)));
typedef __bf16 bf16x4 __attribute__((ext_vector_type(4)));

__device__ __forceinline__ int bucketf(int d){
  float l = log2f((float)d + 1.0f);
  int b = (int)floorf(l);
  return b < 0 ? 0 : (b > 8 ? 8 : b);
}

__global__ void k_deg(const int* __restrict__ src, const int* __restrict__ dst,
                      int* __restrict__ indeg, int* __restrict__ outdeg){
  int e = blockIdx.x*256 + threadIdx.x;
  if(e < EE){
    atomicAdd(&indeg[dst[e]], 1);
    atomicAdd(&outdeg[src[e]], 1);
  }
}

__global__ void k_scan(const int* __restrict__ deg, int* __restrict__ offs){
  __shared__ int part[1024];
  int t = threadIdx.x;
  int v0=deg[t*4], v1=deg[t*4+1], v2=deg[t*4+2], v3=deg[t*4+3];
  int s = v0+v1+v2+v3;
  part[t] = s;
  __syncthreads();
  for(int d=1; d<1024; d<<=1){
    int x = (t>=d) ? part[t-d] : 0;
    __syncthreads();
    part[t] += x;
    __syncthreads();
  }
  int base = (t>0) ? part[t-1] : 0;
  offs[t*4]   = base;
  offs[t*4+1] = base+v0;
  offs[t*4+2] = base+v0+v1;
  offs[t*4+3] = base+v0+v1+v2;
  if(t==1023) offs[4096] = base+s;
}

// scatter edges by dst (CSR build)
__global__ void k_scatter(const int* __restrict__ src, const int* __restrict__ dst,
                          const int* __restrict__ offs, int* __restrict__ cursor,
                          int* __restrict__ elist, int* __restrict__ nsrc){
  int e = blockIdx.x*256+threadIdx.x;
  if(e<EE){
    int d = dst[e], s = src[e];
    int p = atomicAdd(&cursor[d],1);
    int pos = offs[d]+p;
    elist[pos] = e;
    nsrc[pos]  = s;
  }
}

// build F1 row-wise from CSR: no atomics, no pre-zero (full overwrite)
__global__ void k_f1row(const int* __restrict__ offs, const int* __restrict__ nsrc,
                        unsigned* __restrict__ F1){
  int d = blockIdx.x; int w = threadIdx.x;  // 128 threads = 1 word each
  int o0 = offs[d], o1 = offs[d+1];
  unsigned v = 0;
  for(int i=o0;i<o1;i++){
    int s = nsrc[i];
    if((s>>5) == w) v |= 1u << (s&31);
  }
  F1[(size_t)d*FW + w] = v;
}

// CSR propagation: Fout[d] = OR over in-neighbors s of Fin[s]. No atomics.
__global__ void k_prop(const int* __restrict__ offs, const int* __restrict__ nsrc,
                       const unsigned* __restrict__ Fin, unsigned* __restrict__ Fout){
  int d = blockIdx.x; int w = threadIdx.x;  // 128 threads = 1 word each
  int o0 = offs[d], o1 = offs[d+1];
  unsigned v = 0;
  for(int i=o0;i<o1;i++){
    int s = nsrc[i];
    v |= Fin[(size_t)s*FW + w];
  }
  Fout[(size_t)d*FW + w] = v;
}

// fused: x_in = x + deg-bucket embeds ; xn = LN(x_in). one wave per node.
__global__ void k_xin_ln(const float* __restrict__ x, const int* __restrict__ indeg,
                         const int* __restrict__ outdeg, const float* __restrict__ iemb,
                         const float* __restrict__ oemb, const float* __restrict__ g,
                         const float* __restrict__ b, float* __restrict__ x_in,
                         __bf16* __restrict__ xn){
  int node = blockIdx.x*4 + (threadIdx.x >> 6);
  int lane = threadIdx.x & 63;
  int bi = bucketf(indeg[node]);
  int bo = bucketf(outdeg[node]);
  float4 xv = ((const float4*)(x + (size_t)node*CC))[lane];
  float4 iv = ((const float4*)(iemb + (size_t)bi*CC))[lane];
  float4 ov = ((const float4*)(oemb + (size_t)bo*CC))[lane];
  float4 v;
  v.x = xv.x+iv.x+ov.x; v.y = xv.y+iv.y+ov.y;
  v.z = xv.z+iv.z+ov.z; v.w = xv.w+iv.w+ov.w;
  ((float4*)(x_in + (size_t)node*CC))[lane] = v;
  float s  = v.x+v.y+v.z+v.w;
  float sq = v.x*v.x+v.y*v.y+v.z*v.z+v.w*v.w;
  #pragma unroll
  for(int m=32;m>=1;m>>=1){ s += __shfl_xor(s,m); sq += __shfl_xor(sq,m); }
  float mu  = s * (1.0f/CC);
  float var = sq * (1.0f/CC) - mu*mu;
  float inv = rsqrtf(var + 1e-5f);
  float4 gv = ((const float4*)g)[lane];
  float4 bv = ((const float4*)b)[lane];
  bf16x4 o;
  o[0] = (__bf16)(gv.x*(v.x-mu)*inv + bv.x);
  o[1] = (__bf16)(gv.y*(v.y-mu)*inv + bv.y);
  o[2] = (__bf16)(gv.z*(v.z-mu)*inv + bv.z);
  o[3] = (__bf16)(gv.w*(v.w-mu)*inv + bv.w);
  *(bf16x4*)(xn + (size_t)node*CC + lane*4) = o;
}

// LayerNorm (fp32 in, bf16 out): one wave per node
__global__ void k_ln(const float* __restrict__ in, const float* __restrict__ g,
                     const float* __restrict__ b, __bf16* __restrict__ out){
  int node = blockIdx.x*4 + (threadIdx.x >> 6);
  int lane = threadIdx.x & 63;
  float4 v = ((const float4*)(in + (size_t)node*CC))[lane];
  float s  = v.x+v.y+v.z+v.w;
  float sq = v.x*v.x+v.y*v.y+v.z*v.z+v.w*v.w;
  #pragma unroll
  for(int m=32;m>=1;m>>=1){ s += __shfl_xor(s,m); sq += __shfl_xor(sq,m); }
  float mu  = s * (1.0f/CC);
  float var = sq * (1.0f/CC) - mu*mu;
  float inv = rsqrtf(var + 1e-5f);
  float4 gv = ((const float4*)g)[lane];
  float4 bv = ((const float4*)b)[lane];
  bf16x4 o;
  o[0] = (__bf16)(gv.x*(v.x-mu)*inv + bv.x);
  o[1] = (__bf16)(gv.y*(v.y-mu)*inv + bv.y);
  o[2] = (__bf16)(gv.z*(v.z-mu)*inv + bv.z);
  o[3] = (__bf16)(gv.w*(v.w-mu)*inv + bv.w);
  *(bf16x4*)(out + (size_t)node*CC + lane*4) = o;
}

// weight transposes (fp32 [K,N] -> bf16 [N,K]) + qkv bias concat + counter zero.
// blocks: Wq 0-15, Wk 16-31, Wv 32-47, Wo 48-63, W1 64-127, W2 128-191,
// bias 192, zero 193-240.
__global__ void k_pre(const float* __restrict__ Wq, const float* __restrict__ Wk,
                      const float* __restrict__ Wv, const float* __restrict__ Wo,
                      const float* __restrict__ W1, const float* __restrict__ W2,
                      const float* __restrict__ bq, const float* __restrict__ bk,
                      const float* __restrict__ bv,
                      __bf16* __restrict__ WqkvT, __bf16* __restrict__ WoT,
                      __bf16* __restrict__ W1T, __bf16* __restrict__ W2T,
                      float* __restrict__ bqkv, int* __restrict__ zero_base){
  int b = blockIdx.x;
  int tid = threadIdx.x;
  if(b >= 193){
    zero_base[(b-193)*256 + tid] = 0;   // indeg|outdeg|cursor = 12288 ints
    return;
  }
  if(b == 192){
    bqkv[tid]     = bq[tid];
    bqkv[256+tid] = bk[tid];
    bqkv[512+tid] = bv[tid];
    return;
  }
  const float* W; __bf16* Wt; int K, N, tile;
  if(b < 16)      { W=Wq; Wt=WqkvT;        K=256;  N=256;  tile=b; }
  else if(b < 32) { W=Wk; Wt=WqkvT+65536;  K=256;  N=256;  tile=b-16; }
  else if(b < 48) { W=Wv; Wt=WqkvT+131072; K=256;  N=256;  tile=b-32; }
  else if(b < 64) { W=Wo; Wt=WoT;          K=256;  N=256;  tile=b-48; }
  else if(b < 128){ W=W1; Wt=W1T;          K=256;  N=1024; tile=b-64; }
  else            { W=W2; Wt=W2T;          K=1024; N=256;  tile=b-128; }
  int nK = K/64;
  int tk = tile % nK, tn = tile / nK;
  __shared__ float T[64][65];
  int c = tid & 63, r0 = tid >> 6;
  #pragma unroll
  for(int i=0;i<16;i++){
    int row = r0*16 + i;
    T[row][c] = W[(size_t)(tk*64+row)*N + tn*64 + c];
  }
  __syncthreads();
  #pragma unroll
  for(int i=0;i<16;i++){
    int row = r0*16 + i;
    Wt[(size_t)(tn*64+row)*K + tk*64 + c] = (__bf16)T[c][row];
  }
}

// bf16 MFMA GEMM: C[M,N] = A[M,K] @ Bt[N,K]^T + bias
// MODE 0: fp32 out, 1: fp32 out + add, 2: gelu -> bf16 out, 3: bf16 out
template<int MODE>
__global__ __launch_bounds__(256) void k_bgemm(const __bf16* __restrict__ A, const __bf16* __restrict__ Bt,
                       const float* __restrict__ bias, const float* __restrict__ add,
                       float* __restrict__ outf, __bf16* __restrict__ outb,
                       int M, int N, int K){
  __shared__ __bf16 As[64*64];
  __shared__ __bf16 Bs[64*64];
  const int tid = threadIdx.x;
  const int lane = tid & 63, w = tid >> 6;
  const int wr = w >> 1, wc = w & 1;
  const int l15 = lane & 15, g = lane >> 4;
  const int bm = blockIdx.y*64, bn = blockIdx.x*64;
  f32x4 acc[2][2] = {};
  for(int k0=0; k0<K; k0+=64){
    #pragma unroll
    for(int rep=0; rep<2; rep++){
      int q = tid + rep*256;
      int row = q>>3, cb = (q&7)*16;
      int byte_ = row*128 + cb; byte_ ^= (row&7)<<4;
      *(bf16x8*)((char*)As + byte_) = *(const bf16x8*)(A  + (size_t)(bm+row)*K + k0 + (q&7)*8);
      *(bf16x8*)((char*)Bs + byte_) = *(const bf16x8*)(Bt + (size_t)(bn+row)*K + k0 + (q&7)*8);
    }
    __syncthreads();
    #pragma unroll
    for(int ks=0; ks<2; ks++){
      bf16x8 a[2], b[2];
      #pragma unroll
      for(int i=0;i<2;i++){
        int row = wr*32 + i*16 + l15;
        int byte_ = row*128 + ks*64 + g*16; byte_ ^= (row&7)<<4;
        a[i] = *(const bf16x8*)((const char*)As + byte_);
      }
      #pragma unroll
      for(int j=0;j<2;j++){
        int row = wc*32 + j*16 + l15;
        int byte_ = row*128 + ks*64 + g*16; byte_ ^= (row&7)<<4;
        b[j] = *(const bf16x8*)((const char*)Bs + byte_);
      }
      #pragma unroll
      for(int i=0;i<2;i++)
        #pragma unroll
        for(int j=0;j<2;j++)
          acc[i][j] = __builtin_amdgcn_mfma_f32_16x16x32_bf16(a[i], b[j], acc[i][j], 0, 0, 0);
    }
    __syncthreads();
  }
  #pragma unroll
  for(int i=0;i<2;i++){
    #pragma unroll
    for(int j=0;j<2;j++){
      int col = bn + wc*32 + j*16 + l15;
      float bv = bias[col];
      #pragma unroll
      for(int r=0;r<4;r++){
        int rowg = bm + wr*32 + i*16 + g*4 + r;
        float v = acc[i][j][r] + bv;
        if(MODE==1) v += add[(size_t)rowg*N + col];
        if(MODE==2){
          v = 0.5f*v*(1.0f + erff(v*0.70710678118654752f));
          outb[(size_t)rowg*N + col] = (__bf16)v;
        } else if(MODE==3){
          outb[(size_t)rowg*N + col] = (__bf16)v;
        } else {
          outf[(size_t)rowg*N + col] = v;
        }
      }
    }
  }
}

// 4 edges per block, one wave per edge (2 heads x 32 lanes per pass, 4 passes).
// spd probe inlined.
__global__ void k_scores(const int* __restrict__ src, const int* __restrict__ dst,
                         const __bf16* __restrict__ QKV,
                         const unsigned* __restrict__ F1, const unsigned* __restrict__ F2,
                         const unsigned* __restrict__ F3,
                         const float* __restrict__ spde, const float* __restrict__ etb,
                         float* __restrict__ scores){
  int e = blockIdx.x*4 + (threadIdx.x>>6);
  int l = threadIdx.x & 63;
  int c = l & 31;
  int s = src[e], d = dst[e];
  float acc[4];
  #pragma unroll
  for(int p=0;p<4;p++){
    int h = p*2 + (l>>5);
    float q = (float)QKV[(size_t)d*768 + h*DHD + c];
    float k = (float)QKV[(size_t)s*768 + 256 + h*DHD + c];
    float v = q*k;
    #pragma unroll
    for(int mk=16;mk>=1;mk>>=1) v += __shfl_xor(v,mk);
    acc[p] = v;
  }
  if(c==0){
    size_t wi = (size_t)s*FW + (d>>5); unsigned bb = 1u << (d&31);
    int sp = 4;
    if(F3[wi] & bb) sp = 3;
    if(F2[wi] & bb) sp = 2;
    if(F1[wi] & bb) sp = 1;
    float base = etb[0];
    #pragma unroll
    for(int p=0;p<4;p++){
      int h = p*2 + (l>>5);
      scores[(size_t)e*HH+h] = acc[p]*0.17677669529663687f + spde[sp*HH+h] + base;
    }
  }
}

// one block per dst node; 8 heads x 32 lanes; V bf16 from QKV; bf16 msg out
__global__ void k_agg(const int* __restrict__ nsrc, const int* __restrict__ offs,
                      const int* __restrict__ elist, const float* __restrict__ scores,
                      const __bf16* __restrict__ QKV, __bf16* __restrict__ msg){
  int d = blockIdx.x;
  int t = threadIdx.x; int h = t>>5, l = t&31;
  int o0 = offs[d], deg = offs[d+1]-o0;
  float m = -3.0e38f;
  for(int i=l;i<deg;i+=32) m = fmaxf(m, scores[(size_t)elist[o0+i]*HH+h]);
  #pragma unroll
  for(int mk=16;mk>=1;mk>>=1) m = fmaxf(m, __shfl_xor(m,mk));
  float ssum = 0.f;
  for(int i=l;i<deg;i+=32) ssum += expf(scores[(size_t)elist[o0+i]*HH+h]-m);
  #pragma unroll
  for(int mk=16;mk>=1;mk>>=1) ssum += __shfl_xor(ssum,mk);
  float inv = (ssum>0.f) ? 1.f/ssum : 1.f;
  float acc = 0.f;
  for(int i=0;i<deg;i++){
    int e = elist[o0+i];
    int s = nsrc[o0+i];
    float wv = expf(scores[(size_t)e*HH+h]-m)*inv;
    acc += wv * (float)QKV[(size_t)s*768 + 512 + h*DHD + l];
  }
  msg[(size_t)d*CC + h*DHD + l] = (__bf16)acc;
}

extern "C" void kernel_launch(void* const* d_in, const int* in_sizes, int n_in,
                              void* d_out, int out_size, void* d_ws, size_t ws_size,
                              hipStream_t stream){
  const float* x  = (const float*)d_in[0];
  const int*  ei  = (const int*)d_in[1];
  const float* Wq = (const float*)d_in[2];  const float* bq = (const float*)d_in[3];
  const float* Wk = (const float*)d_in[4];  const float* bk = (const float*)d_in[5];
  const float* Wv = (const float*)d_in[6];  const float* bv = (const float*)d_in[7];
  const float* Wo = (const float*)d_in[8];  const float* bo = (const float*)d_in[9];
  const float* W1 = (const float*)d_in[10]; const float* b1 = (const float*)d_in[11];
  const float* W2 = (const float*)d_in[12]; const float* b2 = (const float*)d_in[13];
  const float* g1 = (const float*)d_in[14]; const float* be1= (const float*)d_in[15];
  const float* g2 = (const float*)d_in[16]; const float* be2= (const float*)d_in[17];
  const float* spde = (const float*)d_in[18];
  const float* iemb = (const float*)d_in[19];
  const float* oemb = (const float*)d_in[20];
  const float* etb  = (const float*)d_in[21];
  const int* src = ei;
  const int* dst = ei + EE;
  float* out = (float*)d_out;

  const size_t NC = (size_t)NN*CC;       // 1,048,576 floats
  float* ws   = (float*)d_ws;
  // ---- layout in float words (explicit, non-overlapping among live ranges) ----
  float* x_in = ws;                                   // [0, NC)
  float* hbuf = ws + NC;                              // [NC, 2NC)
  int* indeg  = (int*)(ws + 2*NC);                    // 2NC + [0,4096)
  int* outdeg = indeg + NN;                           // +4096
  int* cursor = outdeg + NN;                          // +4096
  unsigned* F1 = (unsigned*)(cursor + NN);            // 2NC+12288, 524288 words
  unsigned* F2 = F1 + (size_t)NN*FW;                  // +524288
  unsigned* F3 = F2 + (size_t)NN*FW;                  // ends at word 3,682,304
  __bf16* QKV  = (__bf16*)(F3 + (size_t)NN*FW);       // [3,682,304 , 5,255,168) words
  float* scores = ws + 5255168;                       // 262,144 words
  __bf16* xn_bf  = (__bf16*)(ws + 5517312);           // 524,288 words
  __bf16* msg_bf = (__bf16*)(ws + 6041600);           // 524,288 words
  __bf16* WqkvT  = (__bf16*)(ws + 6565888);           // 98,304 words
  __bf16* WoT    = WqkvT + 196608;                    // 32,768 words
  __bf16* W1T    = WoT + 65536;                       // 131,072 words
  __bf16* W2T    = W1T + 262144;                      // 131,072 words -> ends 6,959,104
  float* bqkv    = ws + 6959104;                      // 768
  int* offs      = (int*)(bqkv + 768);                // 4097 (+pad)
  int* elist     = offs + NN + 4;                     // EE
  int* nsrc      = elist + EE;                        // EE  -> ends ~7,029,512 words (28.1 MB)
  // late-phase reuse (regions dead after k_scores/k_agg):
  __bf16* ff1_bf = (__bf16*)(ws + 2*NC);              // [2NC,4NC): over F1-F3 (dead)
  __bf16* hn_bf  = (__bf16*)(ws + 4*NC);              // [4NC,4.5NC): over QKV tail (dead)

  // prep: weight transposes + bias concat + counter zeroing (no runtime fill)
  k_pre<<<241,256,0,stream>>>(Wq,Wk,Wv,Wo,W1,W2,bq,bk,bv,WqkvT,WoT,W1T,W2T,bqkv,indeg);
  k_deg<<<EE/256,256,0,stream>>>(src,dst,indeg,outdeg);
  k_scan<<<1,1024,0,stream>>>(indeg,offs);
  k_scatter<<<EE/256,256,0,stream>>>(src,dst,offs,cursor,elist,nsrc);
  k_f1row<<<NN,FW,0,stream>>>(offs,nsrc,F1);
  k_prop<<<NN,FW,0,stream>>>(offs,nsrc,F1,F2);
  k_prop<<<NN,FW,0,stream>>>(offs,nsrc,F2,F3);
  k_xin_ln<<<NN/4,256,0,stream>>>(x,indeg,outdeg,iemb,oemb,g1,be1,x_in,xn_bf);

  // QKV fused GEMM: [4096,768] bf16 = xn @ [Wq|Wk|Wv]
  dim3 gq(768/64, NN/64);
  k_bgemm<3><<<gq,256,0,stream>>>(xn_bf, WqkvT, bqkv, nullptr, nullptr, QKV, NN, 768, 256);

  k_scores<<<EE/4,256,0,stream>>>(src,dst,QKV,F1,F2,F3,spde,etb,scores);
  k_agg<<<NN,256,0,stream>>>(nsrc,offs,elist,scores,QKV,msg_bf);

  dim3 go(256/64, NN/64);
  k_bgemm<1><<<go,256,0,stream>>>(msg_bf, WoT, bo, x_in, hbuf, nullptr, NN, 256, 256);
  k_ln <<<NN/4,256,0,stream>>>(hbuf,g2,be2,hn_bf);
  dim3 gf1(1024/64, NN/64);
  k_bgemm<2><<<gf1,256,0,stream>>>(hn_bf, W1T, b1, nullptr, nullptr, ff1_bf, NN, 1024, 256);
  dim3 gf2(256/64, NN/64);
  k_bgemm<1><<<gf2,256,0,stream>>>(ff1_bf, W2T, b2, hbuf, out, nullptr, NN, 256, 1024);
}